// Round 1
// baseline (232.947 us; speedup 1.0000x reference)
//
#include <hip/hip_runtime.h>
#include <math.h>

#define GRID_N 256
#define PADN   30
#define GLOB_N 316   // GRID_N + 2*PADN
#define KS     61    // 2*PADN + 1
#define OUT_N  512
#define BATCH  8
#define CHAN   32

// Compute the two 1D Gaussian factor vectors into LDS (first KS threads).
// Reference: make_gaussian with a=1, b=0.5, fwhm1=100, fwhm2=25, computed
// in float64 then cast; kernel[u][v] = 1*g1[u]*g1[v] - 0.5*g2[u]*g2[v].
__device__ __forceinline__ void compute_weights(float* w1, float* w2) {
    int t = threadIdx.x;
    if (t < KS) {
        double d  = (double)(t - PADN);
        double r2 = d * d;
        const double c = 2.772588722239781;  // 4*ln(2)
        w1[t] = (float)exp(-c * r2 / 10000.0); // fwhm1 = 100
        w2[t] = (float)exp(-c * r2 / 625.0);   // fwhm2 = 25
    }
}

// Horizontal separable pass. One block per (batch, global row gi in [0,316)).
// Produces H[b][ch][gi][x], x in [0,256):
//   ch0: sum_v w1[v] * s(gi, x+v)
//   ch1: sum_v w2[v] * s(gi, x+v)
//   ch2: sum_v w1[v] * coord(x+v) * s(gi, x+v)
//   ch3: sum_v w2[v] * coord(x+v) * s(gi, x+v)
// where s is edge-padded xs and coord(j) = (j-30)/255.
__global__ __launch_bounds__(256) void hpass_kernel(const float* __restrict__ xs,
                                                    float* __restrict__ H) {
    __shared__ float srow[GLOB_N];
    __shared__ float w1[KS], w2[KS];
    int b  = blockIdx.x / GLOB_N;
    int gi = blockIdx.x % GLOB_N;
    int t  = threadIdx.x;

    compute_weights(w1, w2);

    int iy = gi - PADN;
    iy = iy < 0 ? 0 : (iy > GRID_N - 1 ? GRID_N - 1 : iy);
    const float* src = xs + ((size_t)b * GRID_N + iy) * GRID_N;
    for (int j = t; j < GLOB_N; j += 256) {
        int ix = j - PADN;
        ix = ix < 0 ? 0 : (ix > GRID_N - 1 ? GRID_N - 1 : ix);
        srow[j] = src[ix];
    }
    __syncthreads();

    float a1 = 0.f, a2 = 0.f, a3 = 0.f, a4 = 0.f;
    for (int v = 0; v < KS; ++v) {
        float s  = srow[t + v];
        float cc = (float)(t + v - PADN) * (1.0f / 255.0f);
        float cs = cc * s;
        float cw1 = w1[v], cw2 = w2[v];
        a1 += cw1 * s;
        a2 += cw2 * s;
        a3 += cw1 * cs;
        a4 += cw2 * cs;
    }
    size_t cst  = (size_t)GLOB_N * GRID_N;
    size_t base = ((size_t)(b * 4) * GLOB_N + gi) * GRID_N + t;
    H[base]           = a1;
    H[base + cst]     = a2;
    H[base + 2 * cst] = a3;
    H[base + 3 * cst] = a4;
}

// Vertical pass + normalize + clip. One block per (batch, output row y).
// Writes g256[b][0][y][x] = xg, g256[b][1][y][x] = yg.
__global__ __launch_bounds__(256) void vpass_kernel(const float* __restrict__ H,
                                                    float* __restrict__ g256) {
    __shared__ float w1[KS], w2[KS];
    int b = blockIdx.x / GRID_N;
    int y = blockIdx.x % GRID_N;
    int t = threadIdx.x;

    compute_weights(w1, w2);
    __syncthreads();

    const float* Hb = H + (size_t)b * 4 * GLOB_N * GRID_N;
    size_t cst = (size_t)GLOB_N * GRID_N;

    float s1 = 0.f, s2 = 0.f, sx1 = 0.f, sx2 = 0.f, sy1 = 0.f, sy2 = 0.f;
    for (int u = 0; u < KS; ++u) {
        size_t off = (size_t)(y + u) * GRID_N + t;
        float h1 = Hb[off];
        float h2 = Hb[off + cst];
        float h3 = Hb[off + 2 * cst];
        float h4 = Hb[off + 3 * cst];
        float cw1 = w1[u], cw2 = w2[u];
        float cc = (float)(y + u - PADN) * (1.0f / 255.0f);
        s1  += cw1 * h1;
        s2  += cw2 * h2;
        sx1 += cw1 * h3;
        sx2 += cw2 * h4;
        sy1 += cw1 * (cc * h1);
        sy2 += cw2 * (cc * h2);
    }
    float p  = s1 - 0.5f * s2;
    float xf = (sx1 - 0.5f * sx2) / p;
    float yf = (sy1 - 0.5f * sy2) / p;
    float xg = fminf(fmaxf(xf * 2.0f - 1.0f, -1.0f), 1.0f);
    float yg = fminf(fmaxf(yf * 2.0f - 1.0f, -1.0f), 1.0f);

    size_t o = (size_t)(b * 2) * GRID_N * GRID_N + (size_t)y * GRID_N + t;
    g256[o] = xg;
    g256[o + (size_t)GRID_N * GRID_N] = yg;
}

// 2x bilinear upsample, jax.image.resize half-pixel semantics:
// src = i*0.5 - 0.25, triangle kernel with edge renormalization == clamp.
__global__ __launch_bounds__(256) void upsample_kernel(const float* __restrict__ g256,
                                                       float* __restrict__ gup) {
    int idx = blockIdx.x * 256 + threadIdx.x;
    int ox = idx & (OUT_N - 1);
    int oy = (idx >> 9) & (OUT_N - 1);
    int b  = idx >> 18;

    float sx = 0.5f * (float)ox - 0.25f;
    float sy = 0.5f * (float)oy - 0.25f;
    float fxf = floorf(sx), fyf = floorf(sy);
    int x0 = (int)fxf, y0 = (int)fyf;
    float fx = sx - fxf, fy = sy - fyf;
    int x0c = x0 < 0 ? 0 : x0;
    int x1c = x0 + 1 > GRID_N - 1 ? GRID_N - 1 : x0 + 1;
    int y0c = y0 < 0 ? 0 : y0;
    int y1c = y0 + 1 > GRID_N - 1 ? GRID_N - 1 : y0 + 1;

    for (int c = 0; c < 2; ++c) {
        const float* g = g256 + ((size_t)(b * 2 + c)) * GRID_N * GRID_N;
        float v00 = g[y0c * GRID_N + x0c];
        float v10 = g[y0c * GRID_N + x1c];
        float v01 = g[y1c * GRID_N + x0c];
        float v11 = g[y1c * GRID_N + x1c];
        float v = (v00 * (1.f - fx) + v10 * fx) * (1.f - fy)
                + (v01 * (1.f - fx) + v11 * fx) * fy;
        gup[((size_t)(b * 2 + c)) * OUT_N * OUT_N + (size_t)oy * OUT_N + ox] = v;
    }
}

// grid_sample bilinear, align_corners=True, zeros padding.
// grid_r = (49*base + grid_up^T)/50. One thread per (b, oy, ox), 32 channels.
__global__ __launch_bounds__(256) void sample_kernel(const float* __restrict__ x,
                                                     const float* __restrict__ gup,
                                                     float* __restrict__ out) {
    int idx = blockIdx.x * 256 + threadIdx.x;
    int ox = idx & (OUT_N - 1);
    int oy = (idx >> 9) & (OUT_N - 1);
    int b  = idx >> 18;

    size_t gplane = (size_t)OUT_N * OUT_N;
    size_t gidx = (size_t)(b * 2) * gplane + (size_t)oy * OUT_N + ox;
    float gxu = gup[gidx];
    float gyu = gup[gidx + gplane];

    float bx = -1.0f + (float)ox * (2.0f / 511.0f);
    float by = -1.0f + (float)oy * (2.0f / 511.0f);
    float gx = (49.0f * bx + gxu) / 50.0f;
    float gy = (49.0f * by + gyu) / 50.0f;

    float pxf = (gx + 1.0f) * 255.5f;  // (W-1)/2 = 255.5
    float pyf = (gy + 1.0f) * 255.5f;
    float fx0 = floorf(pxf), fy0 = floorf(pyf);
    int x0 = (int)fx0, y0 = (int)fy0;
    float fx = pxf - fx0, fy = pyf - fy0;

    float w00 = (1.f - fx) * (1.f - fy);
    float w10 = fx * (1.f - fy);
    float w01 = (1.f - fx) * fy;
    float w11 = fx * fy;

    bool vx0 = (x0 >= 0) && (x0 <= OUT_N - 1);
    bool vx1 = (x0 + 1 >= 0) && (x0 + 1 <= OUT_N - 1);
    bool vy0 = (y0 >= 0) && (y0 <= OUT_N - 1);
    bool vy1 = (y0 + 1 >= 0) && (y0 + 1 <= OUT_N - 1);
    w00 = (vx0 && vy0) ? w00 : 0.f;
    w10 = (vx1 && vy0) ? w10 : 0.f;
    w01 = (vx0 && vy1) ? w01 : 0.f;
    w11 = (vx1 && vy1) ? w11 : 0.f;

    int x0c = x0 < 0 ? 0 : (x0 > OUT_N - 1 ? OUT_N - 1 : x0);
    int x1c = x0 + 1 < 0 ? 0 : (x0 + 1 > OUT_N - 1 ? OUT_N - 1 : x0 + 1);
    int y0c = y0 < 0 ? 0 : (y0 > OUT_N - 1 ? OUT_N - 1 : y0);
    int y1c = y0 + 1 < 0 ? 0 : (y0 + 1 > OUT_N - 1 ? OUT_N - 1 : y0 + 1);

    int o00 = y0c * OUT_N + x0c;
    int o10 = y0c * OUT_N + x1c;
    int o01 = y1c * OUT_N + x0c;
    int o11 = y1c * OUT_N + x1c;

    size_t plane = (size_t)OUT_N * OUT_N;
    const float* xb = x + (size_t)b * CHAN * plane;
    float* ob = out + (size_t)b * CHAN * plane;
    size_t oo = (size_t)oy * OUT_N + ox;

#pragma unroll 4
    for (int c = 0; c < CHAN; ++c) {
        const float* xc = xb + (size_t)c * plane;
        float v = w00 * xc[o00] + w10 * xc[o10] + w01 * xc[o01] + w11 * xc[o11];
        ob[(size_t)c * plane + oo] = v;
    }
}

extern "C" void kernel_launch(void* const* d_in, const int* in_sizes, int n_in,
                              void* d_out, int out_size, void* d_ws, size_t ws_size,
                              hipStream_t stream) {
    (void)in_sizes; (void)n_in; (void)d_ws; (void)ws_size; (void)out_size;
    const float* x  = (const float*)d_in[0];   // (8,32,512,512)
    const float* xs = (const float*)d_in[1];   // (8,1,256,256)
    // d_in[2] = gauss_kernel: recomputed analytically (separable form).

    float* out = (float*)d_out;
    const size_t XS_OUT = (size_t)BATCH * CHAN * OUT_N * OUT_N;  // 67,108,864
    float* gup = out + XS_OUT;  // output 1: grid_up (8,2,512,512)

    // Scratch lives in the x_sampled region of d_out; it is fully
    // overwritten by sample_kernel (which runs after its consumers).
    float* H    = out;                     // 8*4*316*256 = 2,588,672 floats
    float* g256 = out + 4u * 1024 * 1024;  // 8*2*256*256 = 1,048,576 floats

    hipLaunchKernelGGL(hpass_kernel, dim3(BATCH * GLOB_N), dim3(256), 0, stream, xs, H);
    hipLaunchKernelGGL(vpass_kernel, dim3(BATCH * GRID_N), dim3(256), 0, stream, H, g256);
    hipLaunchKernelGGL(upsample_kernel, dim3(BATCH * OUT_N * OUT_N / 256), dim3(256), 0, stream,
                       g256, gup);
    hipLaunchKernelGGL(sample_kernel, dim3(BATCH * OUT_N * OUT_N / 256), dim3(256), 0, stream,
                       x, gup, out);
}